// Round 1
// baseline (456.350 us; speedup 1.0000x reference)
//
#include <hip/hip_runtime.h>

#define FA 75
#define FB 12
#define CC 100
#define NN 20000
#define EE 40000
#define GG 1000
#define BN_EPS 1e-5f

// workspace layout (float offsets)
#define OFF_W1P   0          // packed W1+b1: 7500 rows * 16 floats = 120000
#define OFF_S     0          // S[C,G] = 100000 floats, reuses W1p region AFTER msg
#define OFF_AGG   120000     // aggN [N, C] = 2,000,000
#define OFF_HT    2120000    // h_t  [C, N] = 2,000,000
#define OFF_STAT  4120000    // mean[100] + rstd[100]
#define OFF_START 4120200    // int start[G+1] (1001 ints)
#define OFF_XP    4121216    // xp [N, 80] padded = 1,600,000
// total ~5.73M floats ~= 22.9 MB

// Pack W1 ([FB, FA*C] row-major) + b1 into rows of 16 floats:
// W1p[r*16 + b] = W1[b*7500 + r] (b<12), W1p[r*16+12] = b1[r], rest 0.
__global__ __launch_bounds__(256) void prep_kernel(
    const float* __restrict__ W1, const float* __restrict__ b1,
    float* __restrict__ W1p)
{
    int idx = blockIdx.x * 256 + threadIdx.x;
    if (idx >= 7500 * 16) return;
    int r = idx >> 4, k = idx & 15;
    float v = 0.f;
    if (k < 12) v = W1[k * 7500 + r];
    else if (k == 12) v = b1[r];
    W1p[idx] = v;
}

// pad x rows to 80 floats (16B-aligned rows, zeros in 75..79)
__global__ __launch_bounds__(256) void xpad_kernel(
    const float* __restrict__ x, float* __restrict__ xp)
{
    int idx = blockIdx.x * 256 + threadIdx.x;
    if (idx >= NN * 80) return;
    int n = idx / 80, i = idx - n * 80;
    xp[idx] = (i < FA) ? x[n * FA + i] : 0.f;
}

// molecule row ranges: start[g] = first node of molecule g (batch is sorted)
__global__ __launch_bounds__(256) void start_kernel(
    const int* __restrict__ batch, int* __restrict__ start)
{
    int n = blockIdx.x * 256 + threadIdx.x;
    if (n >= NN) return;
    int b = batch[n];
    int prev = (n == 0) ? -1 : batch[n - 1];
    for (int g = prev + 1; g <= b; ++g) start[g] = n;
    if (n == NN - 1)
        for (int g = b + 1; g <= GG; ++g) start[g] = NN;
}

// Fused NNConv message + scatter.
// Block = 256 threads = 4 waves, all on ONE 5-channel group (cg).
// Weights for the cg staged in LDS (380 rows x 16 floats, rows 375..379 zero
// so the i-loop can run 19 uniform float4 steps; xp pad makes xi=0 there).
// Each thread processes M=4 edges -> LDS broadcast reads amortized 4x
// (keeps LDS return BW at ~119 B/cyc/CU, under the 256 B/cyc ceiling).
// grid = 20 cg * 40 edge-chunks of 1024.
__global__ __launch_bounds__(256) void msg_kernel(
    const float* __restrict__ xp, const float* __restrict__ edge_attr,
    const float* __restrict__ W1p, const int* __restrict__ eidx,
    float* __restrict__ aggN)
{
    __shared__ float wsh[380 * 16];
    const int cg = blockIdx.x % 20;
    const int chunk = blockIdx.x / 20;
    const int cbase = cg * 5;

    // stage weights: LDS row (i*5+j) <- W1p row (i*100 + cbase + j)
    for (int t = threadIdx.x; t < 380 * 4; t += 256) {
        int row = t >> 2, q = t & 3;
        float4 v = make_float4(0.f, 0.f, 0.f, 0.f);
        if (row < 375) {
            int i = row / 5, j = row - i * 5;
            v = *(const float4*)(W1p + ((i * CC + cbase + j) * 16 + q * 4));
        }
        ((float4*)wsh)[t] = v;
    }
    __syncthreads();

    const int e0 = chunk * 1024 + (int)threadIdx.x;
    if (e0 >= EE) return;            // no further barriers below

    int xo[4];                       // float offset of padded x row
    float4 a0[4], a1[4], a2[4];      // edge_attr, 12 floats per edge
#pragma unroll
    for (int m = 0; m < 4; ++m) {
        int e = e0 + m * 256;
        int ec = (e < EE) ? e : 0;
        int src = eidx[ec];
        xo[m] = src * 80;
        const float4* ea4 = (const float4*)(edge_attr + (size_t)ec * FB);
        a0[m] = ea4[0]; a1[m] = ea4[1]; a2[m] = ea4[2];
    }

    float acc[4][5];
#pragma unroll
    for (int m = 0; m < 4; ++m)
#pragma unroll
        for (int j = 0; j < 5; ++j) acc[m][j] = 0.f;

    for (int i4 = 0; i4 < 19; ++i4) {
        float4 xv[4];
#pragma unroll
        for (int m = 0; m < 4; ++m)
            xv[m] = *(const float4*)(xp + xo[m] + i4 * 4);
        const float* wb = wsh + i4 * 320;          // 4 i's * 5 j's * 16
#pragma unroll
        for (int ii = 0; ii < 4; ++ii) {
            const float* wr = wb + ii * 80;
#pragma unroll
            for (int j = 0; j < 5; ++j) {
                const float* w = wr + j * 16;
                float4 w0 = *(const float4*)(w);
                float4 w1 = *(const float4*)(w + 4);
                float4 w2 = *(const float4*)(w + 8);
                float tb = w[12];
#pragma unroll
                for (int m = 0; m < 4; ++m) {
                    float t = tb;
                    t = fmaf(a0[m].x, w0.x, t);
                    t = fmaf(a0[m].y, w0.y, t);
                    t = fmaf(a0[m].z, w0.z, t);
                    t = fmaf(a0[m].w, w0.w, t);
                    t = fmaf(a1[m].x, w1.x, t);
                    t = fmaf(a1[m].y, w1.y, t);
                    t = fmaf(a1[m].z, w1.z, t);
                    t = fmaf(a1[m].w, w1.w, t);
                    t = fmaf(a2[m].x, w2.x, t);
                    t = fmaf(a2[m].y, w2.y, t);
                    t = fmaf(a2[m].z, w2.z, t);
                    t = fmaf(a2[m].w, w2.w, t);
                    t = fmaxf(t, 0.f);
                    float xi = (&xv[m].x)[ii];
                    acc[m][j] = fmaf(xi, t, acc[m][j]);
                }
            }
        }
    }

    // [N][C] layout: 5 consecutive floats per edge -> 1-2 cache lines
#pragma unroll
    for (int m = 0; m < 4; ++m) {
        int e = e0 + m * 256;
        if (e < EE) {
            int dst = eidx[EE + e];
            float* p = aggN + (size_t)dst * CC + cbase;
#pragma unroll
            for (int j = 0; j < 5; ++j) atomicAdd(p + j, acc[m][j]);
        }
    }
}

// h_t[c][n] = relu(x @ W_root + aggN + bias), channel-transposed output.
// lane = node; wave handles a uniform 10-channel group.
__global__ __launch_bounds__(128) void root_kernel(
    const float* __restrict__ x, const float* __restrict__ W_root,
    const float* __restrict__ bias, const float* __restrict__ aggN,
    float* __restrict__ h_t)
{
    const int lane = threadIdx.x & 63;
    const int w = threadIdx.x >> 6;                    // 0..1
    const int nb = blockIdx.x / 5;
    const int cg = (blockIdx.x - nb * 5) * 2 + w;      // 0..9
    const int cbase = __builtin_amdgcn_readfirstlane(cg * 10);
    const int n = nb * 64 + lane;
    const bool ok = (n < NN);
    const int nc = ok ? n : NN - 1;
    const float* xrow = x + (size_t)nc * FA;

    float acc[10];
#pragma unroll
    for (int j = 0; j < 10; ++j) acc[j] = 0.f;

    for (int i = 0; i < FA; ++i) {
        float xi = xrow[i];
        const float* wrow = W_root + i * CC + cbase;   // uniform -> s_load
#pragma unroll
        for (int j = 0; j < 10; ++j) acc[j] = fmaf(xi, wrow[j], acc[j]);
    }

    if (ok) {
        const float* arow = aggN + (size_t)n * CC + cbase;
#pragma unroll
        for (int j = 0; j < 10; ++j) {
            size_t off = (size_t)(cbase + j) * NN + n;
            h_t[off] = fmaxf(acc[j] + bias[cbase + j] + arow[j], 0.f);
        }
    }
}

// per-channel batch mean / rstd over h_t[c][:], coalesced float4 reads
__global__ __launch_bounds__(256) void stats_kernel(
    const float* __restrict__ h_t, float* __restrict__ stats)
{
    const int c = blockIdx.x;   // 0..99
    const float4* row = (const float4*)(h_t + (size_t)c * NN);
    double s = 0.0, s2 = 0.0;
    for (int k = threadIdx.x; k < NN / 4; k += 256) {
        float4 v = row[k];
        s += (double)v.x + (double)v.y + (double)v.z + (double)v.w;
        s2 += (double)v.x * v.x + (double)v.y * v.y
            + (double)v.z * v.z + (double)v.w * v.w;
    }
    __shared__ double sh[256];
    __shared__ double sh2[256];
    sh[threadIdx.x] = s;
    sh2[threadIdx.x] = s2;
    __syncthreads();
    for (int o = 128; o > 0; o >>= 1) {
        if (threadIdx.x < o) {
            sh[threadIdx.x] += sh[threadIdx.x + o];
            sh2[threadIdx.x] += sh2[threadIdx.x + o];
        }
        __syncthreads();
    }
    if (threadIdx.x == 0) {
        double mean = sh[0] / NN;
        double var = sh2[0] / NN - mean * mean;
        stats[c] = (float)mean;
        stats[CC + c] = 1.0f / sqrtf((float)var + BN_EPS);
    }
}

// raw per-(g,c) sums of h_t (BN folded in later algebraically): S[c][g]
__global__ __launch_bounds__(256) void pool_kernel(
    const float* __restrict__ h_t, const int* __restrict__ start,
    float* __restrict__ S)
{
    int t = blockIdx.x * 256 + threadIdx.x;
    if (t >= CC * GG) return;
    int c = t / GG;
    int g = t - c * GG;
    const float* col = h_t + (size_t)c * NN;
    int n1 = start[g + 1];
    float s = 0.f;
    for (int n = start[g]; n < n1; ++n) s += col[n];
    S[t] = s;
}

// out[g] = relu(A_c*S[c,g] + cnt_g*(beta_c - A_c*mean_c)) . W_out + b_out
__global__ __launch_bounds__(128) void out_kernel(
    const float* __restrict__ S, const float* __restrict__ stats,
    const float* __restrict__ gamma, const float* __restrict__ beta,
    const int* __restrict__ start, const float* __restrict__ W_out,
    const float* __restrict__ b_out, float* __restrict__ out)
{
    const int g = blockIdx.x;
    const int c = threadIdx.x;
    float v = 0.f;
    if (c < CC) {
        float mean = stats[c], rstd = stats[CC + c];
        float A = gamma[c] * rstd;
        float B = beta[c] - A * mean;
        float cnt = (float)(start[g + 1] - start[g]);
        float pooled = fmaf(A, S[(size_t)c * GG + g], cnt * B);
        v = fmaxf(pooled, 0.f) * W_out[c];
    }
    __shared__ float sh[128];
    sh[threadIdx.x] = v;
    __syncthreads();
    for (int o = 64; o > 0; o >>= 1) {
        if (threadIdx.x < o) sh[threadIdx.x] += sh[threadIdx.x + o];
        __syncthreads();
    }
    if (threadIdx.x == 0) out[g] = sh[0] + b_out[0];
}

extern "C" void kernel_launch(void* const* d_in, const int* in_sizes, int n_in,
                              void* d_out, int out_size, void* d_ws, size_t ws_size,
                              hipStream_t stream)
{
    const float* x         = (const float*)d_in[0];
    const float* edge_attr = (const float*)d_in[1];
    const float* W1        = (const float*)d_in[2];
    const float* b1        = (const float*)d_in[3];
    const float* W_root    = (const float*)d_in[4];
    const float* bias      = (const float*)d_in[5];
    const float* gamma     = (const float*)d_in[6];
    const float* beta      = (const float*)d_in[7];
    const float* W_out     = (const float*)d_in[8];
    const float* b_out     = (const float*)d_in[9];
    const int*   eidx      = (const int*)d_in[10];
    const int*   batch     = (const int*)d_in[11];

    float* ws    = (float*)d_ws;
    float* W1p   = ws + OFF_W1P;
    float* S     = ws + OFF_S;      // aliases W1p; used only after msg
    float* aggN  = ws + OFF_AGG;
    float* h_t   = ws + OFF_HT;
    float* stats = ws + OFF_STAT;
    int*   start = (int*)(ws + OFF_START);
    float* xp    = ws + OFF_XP;
    float* out   = (float*)d_out;

    hipMemsetAsync(aggN, 0, (size_t)NN * CC * sizeof(float), stream);

    prep_kernel<<<(7500 * 16 + 255) / 256, 256, 0, stream>>>(W1, b1, W1p);
    xpad_kernel<<<(NN * 80 + 255) / 256, 256, 0, stream>>>(x, xp);
    start_kernel<<<(NN + 255) / 256, 256, 0, stream>>>(batch, start);
    msg_kernel<<<20 * 40, 256, 0, stream>>>(xp, edge_attr, W1p, eidx, aggN);
    root_kernel<<<((NN + 63) / 64) * 5, 128, 0, stream>>>(x, W_root, bias, aggN, h_t);
    stats_kernel<<<CC, 256, 0, stream>>>(h_t, stats);
    pool_kernel<<<(CC * GG + 255) / 256, 256, 0, stream>>>(h_t, start, S);
    out_kernel<<<GG, 128, 0, stream>>>(S, stats, gamma, beta, start, W_out, b_out, out);
}

// Round 5
// 430.808 us; speedup vs baseline: 1.0593x; 1.0593x over previous
//
#include <hip/hip_runtime.h>

#define FA 75
#define FB 12
#define CC 100
#define NN 20000
#define EE 40000
#define GG 1000
#define BN_EPS 1e-5f
#define CP 112            // padded channel count (7 chunks of 16)
#define NCH 7

// workspace layout (float offsets)
#define OFF_W2    0                   // w2 [75][13][112] = 109200
#define OFF_WR2   109200              // wr2 [76][112] = 8512 (row 75 = bias)
#define OFF_AGG   117712              // aggN [N][100] = 2,000,000 (16B aligned)
#define OFF_STAT  2117712             // f64 stats[200] = 400 floats (8B aligned)
#define OFF_H     2118112             // h [N][100] = 2,000,000
#define OFF_START 4118112             // int start[1001]
// total ~4.12M floats ~= 16.5 MB

// Repack weights:
//  w2[i][b][c]  (c padded to 112): b<12 -> W1[b][i*100+c], b==12 -> b1[i*100+c]
//  wr2[i][c]    (i<75 -> W_root[i][c], i==75 -> bias[c])
__global__ __launch_bounds__(256) void prep_kernel(
    const float* __restrict__ W1, const float* __restrict__ b1,
    const float* __restrict__ W_root, const float* __restrict__ bias,
    float* __restrict__ w2, float* __restrict__ wr2)
{
    int idx = blockIdx.x * 256 + threadIdx.x;
    if (idx < FA * 13 * CP) {
        int i = idx / (13 * CP);
        int r = idx - i * (13 * CP);
        int b = r / CP;
        int c = r - b * CP;
        float v = 0.f;
        if (c < CC) {
            if (b < 12) v = W1[b * (FA * CC) + i * CC + c];
            else        v = b1[i * CC + c];
        }
        w2[idx] = v;
    } else {
        int j = idx - FA * 13 * CP;
        if (j < 76 * CP) {
            int i = j / CP, c = j - i * CP;
            float v = 0.f;
            if (c < CC) v = (i < FA) ? W_root[i * CC + c] : bias[c];
            wr2[j] = v;
        }
    }
}

// molecule row ranges: start[g] = first node of molecule g (batch is sorted)
__global__ __launch_bounds__(256) void start_kernel(
    const int* __restrict__ batch, int* __restrict__ start)
{
    int n = blockIdx.x * 256 + threadIdx.x;
    if (n >= NN) return;
    int b = batch[n];
    int prev = (n == 0) ? -1 : batch[n - 1];
    for (int g = prev + 1; g <= b; ++g) start[g] = n;
    if (n == NN - 1)
        for (int g = b + 1; g <= GG; ++g) start[g] = NN;
}

// Fused NNConv message + scatter, lane = (edge-sub, channel-sub).
// Wave: 8 edges x 16 channels; lane = se(2b) x c15(4b); per lane 2 edges (A,B).
// Chunk loop (7) covers 112 padded channels; per i: 13 coalesced w-loads
// (64B line each, broadcast across the 4 se-groups) + 28 FMA (the floor).
// __syncthreads per chunk keeps the block's 4 waves L1-phase-locked.
__global__ __launch_bounds__(256) void msg_kernel(
    const float* __restrict__ x, const float* __restrict__ edge_attr,
    const float* __restrict__ w2, const int* __restrict__ eidx,
    float* __restrict__ aggN)
{
    const int lane = threadIdx.x & 63;
    const int wv = threadIdx.x >> 6;
    const int se = lane >> 4;
    const int c15 = lane & 15;
    const int we = blockIdx.x * 32 + wv * 8;
    const int eA = we + se;
    const int eB = we + 4 + se;

    const int srcA = eidx[eA], srcB = eidx[eB];
    const int dstA = eidx[EE + eA], dstB = eidx[EE + eB];

    const float4* pA = (const float4*)(edge_attr + (size_t)eA * FB);
    const float4* pB = (const float4*)(edge_attr + (size_t)eB * FB);
    float4 A0 = pA[0], A1 = pA[1], A2 = pA[2];
    float4 B0 = pB[0], B1 = pB[1], B2 = pB[2];

    const float* xA = x + (size_t)srcA * FA;
    const float* xB = x + (size_t)srcB * FA;

    for (int chunk = 0; chunk < NCH; ++chunk) {
        __syncthreads();                       // phase-lock waves for L1 reuse
        const float* wp = w2 + chunk * 16 + c15;
        float accA = 0.f, accB = 0.f;
        for (int i = 0; i < FA; ++i) {
            const float* wr = wp + i * (13 * CP);
            float w0  = wr[0 * CP];
            float w1  = wr[1 * CP];
            float w2v = wr[2 * CP];
            float w3  = wr[3 * CP];
            float w4  = wr[4 * CP];
            float w5  = wr[5 * CP];
            float w6  = wr[6 * CP];
            float w7  = wr[7 * CP];
            float w8  = wr[8 * CP];
            float w9  = wr[9 * CP];
            float w10 = wr[10 * CP];
            float w11 = wr[11 * CP];
            float w12 = wr[12 * CP];
            float xiA = xA[i];
            float xiB = xB[i];
            float tA = w12, tB = w12;
            tA = fmaf(A0.x, w0,  tA);  tB = fmaf(B0.x, w0,  tB);
            tA = fmaf(A0.y, w1,  tA);  tB = fmaf(B0.y, w1,  tB);
            tA = fmaf(A0.z, w2v, tA);  tB = fmaf(B0.z, w2v, tB);
            tA = fmaf(A0.w, w3,  tA);  tB = fmaf(B0.w, w3,  tB);
            tA = fmaf(A1.x, w4,  tA);  tB = fmaf(B1.x, w4,  tB);
            tA = fmaf(A1.y, w5,  tA);  tB = fmaf(B1.y, w5,  tB);
            tA = fmaf(A1.z, w6,  tA);  tB = fmaf(B1.z, w6,  tB);
            tA = fmaf(A1.w, w7,  tA);  tB = fmaf(B1.w, w7,  tB);
            tA = fmaf(A2.x, w8,  tA);  tB = fmaf(B2.x, w8,  tB);
            tA = fmaf(A2.y, w9,  tA);  tB = fmaf(B2.y, w9,  tB);
            tA = fmaf(A2.z, w10, tA);  tB = fmaf(B2.z, w10, tB);
            tA = fmaf(A2.w, w11, tA);  tB = fmaf(B2.w, w11, tB);
            tA = fmaxf(tA, 0.f);       tB = fmaxf(tB, 0.f);
            accA = fmaf(xiA, tA, accA);
            accB = fmaf(xiB, tB, accB);
        }
        int cc = chunk * 16 + c15;
        if (cc < CC) {
            atomicAdd(&aggN[(size_t)dstA * CC + cc], accA);
            atomicAdd(&aggN[(size_t)dstB * CC + cc], accB);
        }
    }
}

// h[n][c] = relu(x @ W_root + aggN + bias), natural [N][C] layout.
// Same lane mapping: 4 nodes x 16 channels per wave, 7 chunks, i-outer.
__global__ __launch_bounds__(256) void root_kernel(
    const float* __restrict__ x, const float* __restrict__ wr2,
    const float* __restrict__ aggN, float* __restrict__ h)
{
    const int lane = threadIdx.x & 63;
    const int wv = threadIdx.x >> 6;
    const int se = lane >> 4;
    const int c15 = lane & 15;
    const int n = blockIdx.x * 16 + wv * 4 + se;

    const float* xr = x + (size_t)n * FA;
    float acc[NCH];
#pragma unroll
    for (int k = 0; k < NCH; ++k) acc[k] = 0.f;

    for (int i = 0; i < FA; ++i) {
        float xi = xr[i];
        const float* wr = wr2 + i * CP + c15;
#pragma unroll
        for (int k = 0; k < NCH; ++k) acc[k] = fmaf(xi, wr[k * 16], acc[k]);
    }

#pragma unroll
    for (int k = 0; k < NCH; ++k) {
        int cc = k * 16 + c15;
        if (cc < CC) {
            float b = wr2[FA * CP + cc];     // bias row
            float v = acc[k] + b + aggN[(size_t)n * CC + cc];
            h[(size_t)n * CC + cc] = fmaxf(v, 0.f);
        }
    }
}

// per-channel sum / sumsq over h[:, c] via f64 atomics (125 partials/channel)
__global__ __launch_bounds__(128) void stats_kernel(
    const float* __restrict__ h, double* __restrict__ stats)
{
    const int c = threadIdx.x;
    if (c >= CC) return;
    const int n0 = blockIdx.x * 160;         // grid 125 -> 20000 nodes
    double s = 0.0, s2 = 0.0;
    for (int n = n0; n < n0 + 160; ++n) {
        float v = h[(size_t)n * CC + c];
        s += (double)v;
        s2 += (double)v * (double)v;
    }
    atomicAdd(&stats[c], s);
    atomicAdd(&stats[CC + c], s2);
}

// fused pool + BN-fold + relu + dot(W_out):
// out[g] = relu(A_c*sum_n h[n][c] + cnt_g*(beta_c - A_c*mean_c)) . W_out + b_out
__global__ __launch_bounds__(128) void poolout_kernel(
    const float* __restrict__ h, const double* __restrict__ stats,
    const float* __restrict__ gamma, const float* __restrict__ beta,
    const int* __restrict__ start, const float* __restrict__ W_out,
    const float* __restrict__ b_out, float* __restrict__ out)
{
    const int g = blockIdx.x;
    const int c = threadIdx.x;
    const int n0 = start[g], n1 = start[g + 1];
    float v = 0.f;
    if (c < CC) {
        float s = 0.f;
        for (int n = n0; n < n1; ++n) s += h[(size_t)n * CC + c];
        double m = stats[c] / NN;
        double var = stats[CC + c] / NN - m * m;
        float mean = (float)m;
        float rstd = rsqrtf((float)var + BN_EPS);
        float A = gamma[c] * rstd;
        float B = beta[c] - A * mean;
        float pooled = fmaf(A, s, (float)(n1 - n0) * B);
        v = fmaxf(pooled, 0.f) * W_out[c];
    }
    __shared__ float sh[128];
    sh[threadIdx.x] = v;
    __syncthreads();
    for (int o = 64; o > 0; o >>= 1) {
        if (threadIdx.x < o) sh[threadIdx.x] += sh[threadIdx.x + o];
        __syncthreads();
    }
    if (threadIdx.x == 0) out[g] = sh[0] + b_out[0];
}

extern "C" void kernel_launch(void* const* d_in, const int* in_sizes, int n_in,
                              void* d_out, int out_size, void* d_ws, size_t ws_size,
                              hipStream_t stream)
{
    const float* x         = (const float*)d_in[0];
    const float* edge_attr = (const float*)d_in[1];
    const float* W1        = (const float*)d_in[2];
    const float* b1        = (const float*)d_in[3];
    const float* W_root    = (const float*)d_in[4];
    const float* bias      = (const float*)d_in[5];
    const float* gamma     = (const float*)d_in[6];
    const float* beta      = (const float*)d_in[7];
    const float* W_out     = (const float*)d_in[8];
    const float* b_out     = (const float*)d_in[9];
    const int*   eidx      = (const int*)d_in[10];
    const int*   batch     = (const int*)d_in[11];

    float*  ws    = (float*)d_ws;
    float*  w2    = ws + OFF_W2;
    float*  wr2   = ws + OFF_WR2;
    float*  aggN  = ws + OFF_AGG;
    double* stats = (double*)(ws + OFF_STAT);
    float*  h     = ws + OFF_H;
    int*    start = (int*)(ws + OFF_START);
    float*  out   = (float*)d_out;

    // zero aggN (2,000,000 f32) + stats (200 f64) in one contiguous memset
    hipMemsetAsync(aggN, 0, (size_t)(2000000 + 400) * sizeof(float), stream);

    prep_kernel<<<(FA * 13 * CP + 76 * CP + 255) / 256, 256, 0, stream>>>(
        W1, b1, W_root, bias, w2, wr2);
    start_kernel<<<(NN + 255) / 256, 256, 0, stream>>>(batch, start);
    msg_kernel<<<EE / 32, 256, 0, stream>>>(x, edge_attr, w2, eidx, aggN);
    root_kernel<<<NN / 16, 256, 0, stream>>>(x, wr2, aggN, h);
    stats_kernel<<<125, 128, 0, stream>>>(h, stats);
    poolout_kernel<<<GG, 128, 0, stream>>>(h, stats, gamma, beta, start,
                                           W_out, b_out, out);
}

// Round 14
// 423.356 us; speedup vs baseline: 1.0779x; 1.0176x over previous
//
#include <hip/hip_runtime.h>

#define FA 75
#define FB 12
#define CC 100
#define NN 20000
#define EE 40000
#define GG 1000
#define BN_EPS 1e-5f
#define CP 112            // padded channel count (7 chunks of 16)
#define NCH 7
#define EBLK 1250         // edge-blocks (32 edges each)

// workspace layout (float offsets)
#define OFF_W2    0                   // w2 [75][13][112] = 109200
#define OFF_WR2   109200              // wr2 [76][112] = 8512 (row 75 = bias)
#define OFF_AGG   117712              // aggN [N][100] = 2,000,000 (16B aligned)
#define OFF_STAT  2117712             // f64 stats[200] = 400 floats (8B aligned)
#define OFF_H     2118112             // h [N][100] = 2,000,000
#define OFF_START 4118112             // int start[1001]
// total ~4.12M floats ~= 16.5 MB

// Repack weights:
//  w2[i][b][c]  (c padded to 112): b<12 -> W1[b][i*100+c], b==12 -> b1[i*100+c]
//  wr2[i][c]    (i<75 -> W_root[i][c], i==75 -> bias[c])
__global__ __launch_bounds__(256) void prep_kernel(
    const float* __restrict__ W1, const float* __restrict__ b1,
    const float* __restrict__ W_root, const float* __restrict__ bias,
    float* __restrict__ w2, float* __restrict__ wr2)
{
    int idx = blockIdx.x * 256 + threadIdx.x;
    if (idx < FA * 13 * CP) {
        int i = idx / (13 * CP);
        int r = idx - i * (13 * CP);
        int b = r / CP;
        int c = r - b * CP;
        float v = 0.f;
        if (c < CC) {
            if (b < 12) v = W1[b * (FA * CC) + i * CC + c];
            else        v = b1[i * CC + c];
        }
        w2[idx] = v;
    } else {
        int j = idx - FA * 13 * CP;
        if (j < 76 * CP) {
            int i = j / CP, c = j - i * CP;
            float v = 0.f;
            if (c < CC) v = (i < FA) ? W_root[i * CC + c] : bias[c];
            wr2[j] = v;
        }
    }
}

// molecule row ranges: start[g] = first node of molecule g (batch is sorted)
__global__ __launch_bounds__(256) void start_kernel(
    const int* __restrict__ batch, int* __restrict__ start)
{
    int n = blockIdx.x * 256 + threadIdx.x;
    if (n >= NN) return;
    int b = batch[n];
    int prev = (n == 0) ? -1 : batch[n - 1];
    for (int g = prev + 1; g <= b; ++g) start[g] = n;
    if (n == NN - 1)
        for (int g = b + 1; g <= GG; ++g) start[g] = NN;
}

// Fused NNConv message + scatter, lane = (edge-sub, channel-sub).
// One CHANNEL CHUNK per block (chunk loop hoisted into the grid, chunk-major):
// attrs' live range spans a single chunk -> no register starvation (the
// round-5 VGPR=32 sink/reload pathology), and 8750 blocks feed occupancy.
// Wave: 8 edges x 16 channels; lane = se(2b) x c15(4b); per lane 2 edges.
// Per i: 13 coalesced w-loads (64B line each, shared by the 4 se-groups)
// + 28 FMA (the 14-op/(e,c) floor).
__global__ __launch_bounds__(256, 8) void msg_kernel(
    const float* __restrict__ x, const float* __restrict__ edge_attr,
    const float* __restrict__ w2, const int* __restrict__ eidx,
    float* __restrict__ aggN)
{
    const int chunk = blockIdx.x / EBLK;           // 0..6  (chunk-major)
    const int eb    = blockIdx.x - chunk * EBLK;   // 0..1249
    const int lane = threadIdx.x & 63;
    const int wv = threadIdx.x >> 6;
    const int se = lane >> 4;
    const int c15 = lane & 15;
    const int we = eb * 32 + wv * 8;
    const int eA = we + se;
    const int eB = we + 4 + se;

    const int srcA = eidx[eA], srcB = eidx[eB];
    const int dstA = eidx[EE + eA], dstB = eidx[EE + eB];

    const float4* pA = (const float4*)(edge_attr + (size_t)eA * FB);
    const float4* pB = (const float4*)(edge_attr + (size_t)eB * FB);
    float4 A0 = pA[0], A1 = pA[1], A2 = pA[2];
    float4 B0 = pB[0], B1 = pB[1], B2 = pB[2];

    const float* xA = x + (size_t)srcA * FA;
    const float* xB = x + (size_t)srcB * FA;

    const float* wp = w2 + chunk * 16 + c15;
    float accA = 0.f, accB = 0.f;
#pragma unroll 2
    for (int i = 0; i < FA; ++i) {
        const float* wr = wp + i * (13 * CP);
        float w0  = wr[0 * CP];
        float w1  = wr[1 * CP];
        float w2v = wr[2 * CP];
        float w3  = wr[3 * CP];
        float w4  = wr[4 * CP];
        float w5  = wr[5 * CP];
        float w6  = wr[6 * CP];
        float w7  = wr[7 * CP];
        float w8  = wr[8 * CP];
        float w9  = wr[9 * CP];
        float w10 = wr[10 * CP];
        float w11 = wr[11 * CP];
        float w12 = wr[12 * CP];
        float xiA = xA[i];
        float xiB = xB[i];
        float tA = w12, tB = w12;
        tA = fmaf(A0.x, w0,  tA);  tB = fmaf(B0.x, w0,  tB);
        tA = fmaf(A0.y, w1,  tA);  tB = fmaf(B0.y, w1,  tB);
        tA = fmaf(A0.z, w2v, tA);  tB = fmaf(B0.z, w2v, tB);
        tA = fmaf(A0.w, w3,  tA);  tB = fmaf(B0.w, w3,  tB);
        tA = fmaf(A1.x, w4,  tA);  tB = fmaf(B1.x, w4,  tB);
        tA = fmaf(A1.y, w5,  tA);  tB = fmaf(B1.y, w5,  tB);
        tA = fmaf(A1.z, w6,  tA);  tB = fmaf(B1.z, w6,  tB);
        tA = fmaf(A1.w, w7,  tA);  tB = fmaf(B1.w, w7,  tB);
        tA = fmaf(A2.x, w8,  tA);  tB = fmaf(B2.x, w8,  tB);
        tA = fmaf(A2.y, w9,  tA);  tB = fmaf(B2.y, w9,  tB);
        tA = fmaf(A2.z, w10, tA);  tB = fmaf(B2.z, w10, tB);
        tA = fmaf(A2.w, w11, tA);  tB = fmaf(B2.w, w11, tB);
        tA = fmaxf(tA, 0.f);       tB = fmaxf(tB, 0.f);
        accA = fmaf(xiA, tA, accA);
        accB = fmaf(xiB, tB, accB);
    }
    int cc = chunk * 16 + c15;
    if (cc < CC) {
        atomicAdd(&aggN[(size_t)dstA * CC + cc], accA);
        atomicAdd(&aggN[(size_t)dstB * CC + cc], accB);
    }
}

// h[n][c] = relu(x @ W_root + aggN + bias), natural [N][C] layout.
// Same lane mapping: 4 nodes x 16 channels per wave, 7 chunks, i-outer.
__global__ __launch_bounds__(256) void root_kernel(
    const float* __restrict__ x, const float* __restrict__ wr2,
    const float* __restrict__ aggN, float* __restrict__ h)
{
    const int lane = threadIdx.x & 63;
    const int wv = threadIdx.x >> 6;
    const int se = lane >> 4;
    const int c15 = lane & 15;
    const int n = blockIdx.x * 16 + wv * 4 + se;

    const float* xr = x + (size_t)n * FA;
    float acc[NCH];
#pragma unroll
    for (int k = 0; k < NCH; ++k) acc[k] = 0.f;

    for (int i = 0; i < FA; ++i) {
        float xi = xr[i];
        const float* wr = wr2 + i * CP + c15;
#pragma unroll
        for (int k = 0; k < NCH; ++k) acc[k] = fmaf(xi, wr[k * 16], acc[k]);
    }

#pragma unroll
    for (int k = 0; k < NCH; ++k) {
        int cc = k * 16 + c15;
        if (cc < CC) {
            float b = wr2[FA * CP + cc];     // bias row
            float v = acc[k] + b + aggN[(size_t)n * CC + cc];
            h[(size_t)n * CC + cc] = fmaxf(v, 0.f);
        }
    }
}

// per-channel sum / sumsq over h[:, c] via f64 atomics (125 partials/channel)
__global__ __launch_bounds__(128) void stats_kernel(
    const float* __restrict__ h, double* __restrict__ stats)
{
    const int c = threadIdx.x;
    if (c >= CC) return;
    const int n0 = blockIdx.x * 160;         // grid 125 -> 20000 nodes
    double s = 0.0, s2 = 0.0;
    for (int n = n0; n < n0 + 160; ++n) {
        float v = h[(size_t)n * CC + c];
        s += (double)v;
        s2 += (double)v * (double)v;
    }
    atomicAdd(&stats[c], s);
    atomicAdd(&stats[CC + c], s2);
}

// fused pool + BN-fold + relu + dot(W_out):
// out[g] = relu(A_c*sum_n h[n][c] + cnt_g*(beta_c - A_c*mean_c)) . W_out + b_out
__global__ __launch_bounds__(128) void poolout_kernel(
    const float* __restrict__ h, const double* __restrict__ stats,
    const float* __restrict__ gamma, const float* __restrict__ beta,
    const int* __restrict__ start, const float* __restrict__ W_out,
    const float* __restrict__ b_out, float* __restrict__ out)
{
    const int g = blockIdx.x;
    const int c = threadIdx.x;
    const int n0 = start[g], n1 = start[g + 1];
    float v = 0.f;
    if (c < CC) {
        float s = 0.f;
        for (int n = n0; n < n1; ++n) s += h[(size_t)n * CC + c];
        double m = stats[c] / NN;
        double var = stats[CC + c] / NN - m * m;
        float mean = (float)m;
        float rstd = rsqrtf((float)var + BN_EPS);
        float A = gamma[c] * rstd;
        float B = beta[c] - A * mean;
        float pooled = fmaf(A, s, (float)(n1 - n0) * B);
        v = fmaxf(pooled, 0.f) * W_out[c];
    }
    __shared__ float sh[128];
    sh[threadIdx.x] = v;
    __syncthreads();
    for (int o = 64; o > 0; o >>= 1) {
        if (threadIdx.x < o) sh[threadIdx.x] += sh[threadIdx.x + o];
        __syncthreads();
    }
    if (threadIdx.x == 0) out[g] = sh[0] + b_out[0];
}

extern "C" void kernel_launch(void* const* d_in, const int* in_sizes, int n_in,
                              void* d_out, int out_size, void* d_ws, size_t ws_size,
                              hipStream_t stream)
{
    const float* x         = (const float*)d_in[0];
    const float* edge_attr = (const float*)d_in[1];
    const float* W1        = (const float*)d_in[2];
    const float* b1        = (const float*)d_in[3];
    const float* W_root    = (const float*)d_in[4];
    const float* bias      = (const float*)d_in[5];
    const float* gamma     = (const float*)d_in[6];
    const float* beta      = (const float*)d_in[7];
    const float* W_out     = (const float*)d_in[8];
    const float* b_out     = (const float*)d_in[9];
    const int*   eidx      = (const int*)d_in[10];
    const int*   batch     = (const int*)d_in[11];

    float*  ws    = (float*)d_ws;
    float*  w2    = ws + OFF_W2;
    float*  wr2   = ws + OFF_WR2;
    float*  aggN  = ws + OFF_AGG;
    double* stats = (double*)(ws + OFF_STAT);
    float*  h     = ws + OFF_H;
    int*    start = (int*)(ws + OFF_START);
    float*  out   = (float*)d_out;

    // zero aggN (2,000,000 f32) + stats (200 f64) in one contiguous memset
    hipMemsetAsync(aggN, 0, (size_t)(2000000 + 400) * sizeof(float), stream);

    prep_kernel<<<(FA * 13 * CP + 76 * CP + 255) / 256, 256, 0, stream>>>(
        W1, b1, W_root, bias, w2, wr2);
    start_kernel<<<(NN + 255) / 256, 256, 0, stream>>>(batch, start);
    msg_kernel<<<NCH * EBLK, 256, 0, stream>>>(x, edge_attr, w2, eidx, aggN);
    root_kernel<<<NN / 16, 256, 0, stream>>>(x, wr2, aggN, h);
    stats_kernel<<<125, 128, 0, stream>>>(h, stats);
    poolout_kernel<<<GG, 128, 0, stream>>>(h, stats, gamma, beta, start,
                                           W_out, b_out, out);
}

// Round 15
// 281.976 us; speedup vs baseline: 1.6184x; 1.5014x over previous
//
#include <hip/hip_runtime.h>

#define FA 75
#define FB 12
#define CC 100
#define NN 20000
#define EE 40000
#define GG 1000
#define BN_EPS 1e-5f
#define CP 112            // padded channels for root_kernel (7 chunks of 16)
#define NCH 7
#define CW 128            // padded channels for msg weights (2 waves x 64)

// workspace layout (float offsets)
#define OFF_W3    0                   // w3 [75][13][128] = 124800
#define OFF_WR2   124800              // wr2 [76][112] = 8512 (row 75 = bias)
#define OFF_AGG   133312              // aggN [N][100] = 2,000,000 (16B aligned)
#define OFF_STAT  2133312             // f64 stats[200] = 400 floats (8B aligned)
#define OFF_H     2133712             // h [N][100] = 2,000,000
#define OFF_START 4133712             // int start[1001]
// total ~4.13M floats ~= 16.5 MB

// Repack weights:
//  w3[(i*13+b)*128 + c] (c padded to 128): b<12 -> W1[b][i*100+c], b==12 -> b1[i*100+c]
//  wr2[i][c] (c padded to 112): i<75 -> W_root[i][c], i==75 -> bias[c]
__global__ __launch_bounds__(256) void prep_kernel(
    const float* __restrict__ W1, const float* __restrict__ b1,
    const float* __restrict__ W_root, const float* __restrict__ bias,
    float* __restrict__ w3, float* __restrict__ wr2)
{
    int idx = blockIdx.x * 256 + threadIdx.x;
    if (idx < FA * 13 * CW) {
        int i = idx / (13 * CW);
        int r = idx - i * (13 * CW);
        int b = r / CW;
        int c = r - b * CW;
        float v = 0.f;
        if (c < CC) {
            if (b < 12) v = W1[b * (FA * CC) + i * CC + c];
            else        v = b1[i * CC + c];
        }
        w3[idx] = v;
    } else {
        int j = idx - FA * 13 * CW;
        if (j < 76 * CP) {
            int i = j / CP, c = j - i * CP;
            float v = 0.f;
            if (c < CC) v = (i < FA) ? W_root[i * CC + c] : bias[c];
            wr2[j] = v;
        }
    }
}

// molecule row ranges: start[g] = first node of molecule g (batch is sorted)
__global__ __launch_bounds__(256) void start_kernel(
    const int* __restrict__ batch, int* __restrict__ start)
{
    int n = blockIdx.x * 256 + threadIdx.x;
    if (n >= NN) return;
    int b = batch[n];
    int prev = (n == 0) ? -1 : batch[n - 1];
    for (int g = prev + 1; g <= b; ++g) start[g] = n;
    if (n == NN - 1)
        for (int g = b + 1; g <= GG; ++g) start[g] = NN;
}

// Fused NNConv message + scatter — VMEM-instruction-minimal mapping.
// Round-14 diagnosis: 39.4M VMEM instrs (13 w-loads serving only 8e x 16c)
// saturate the TA pipe (~4cyc/wave-load -> 256us floor). New mapping:
// lane = CHANNEL (64/wave; 2 waves cover 128 padded), edges WAVE-UNIFORM
// (8/wave, attrs in 96 VGPRs, loop-invariant), x staged in LDS (off the
// TA path). Per i: 13 VMEM serve 8e x 64c -> 4x fewer VMEM; x/attr read
// once instead of 7x. Block = 4 waves = 2 edge-groups x 2 channel-halves.
__global__ __launch_bounds__(256, 2) void msg_kernel(
    const float* __restrict__ x, const float* __restrict__ edge_attr,
    const float* __restrict__ w3, const int* __restrict__ eidx,
    float* __restrict__ aggN)
{
    __shared__ float xs[16][76];
    const int eb = blockIdx.x * 16;            // 16 edges per block

    for (int t = threadIdx.x; t < 16 * 76; t += 256) {
        int m = t / 76, i = t - m * 76;
        if (i < FA) xs[m][i] = x[(size_t)eidx[eb + m] * FA + i];
    }
    __syncthreads();

    const int wv   = threadIdx.x >> 6;         // 0..3
    const int lane = threadIdx.x & 63;
    const int grp  = wv >> 1;                  // edge group 0..1
    const int half = wv & 1;                   // channel half 0..1
    const int c    = half * 64 + lane;         // 0..127
    const int e0   = eb + grp * 8;

    // 8 edges' attrs, loop-invariant in VGPRs (values wave-uniform)
    float4 A0[8], A1[8], A2[8];
#pragma unroll
    for (int m = 0; m < 8; ++m) {
        const float4* p = (const float4*)(edge_attr + (size_t)(e0 + m) * FB);
        A0[m] = p[0]; A1[m] = p[1]; A2[m] = p[2];
    }

    float acc[8];
#pragma unroll
    for (int m = 0; m < 8; ++m) acc[m] = 0.f;

    const float* wp = w3 + c;
    for (int i = 0; i < FA; ++i) {
        const float* wr = wp + i * (13 * CW);
        float w0  = wr[0 * CW];
        float w1  = wr[1 * CW];
        float w2  = wr[2 * CW];
        float w3v = wr[3 * CW];
        float w4  = wr[4 * CW];
        float w5  = wr[5 * CW];
        float w6  = wr[6 * CW];
        float w7  = wr[7 * CW];
        float w8  = wr[8 * CW];
        float w9  = wr[9 * CW];
        float w10 = wr[10 * CW];
        float w11 = wr[11 * CW];
        float w12 = wr[12 * CW];
#pragma unroll
        for (int m = 0; m < 8; ++m) {
            float t = w12;
            t = fmaf(A0[m].x, w0,  t);
            t = fmaf(A0[m].y, w1,  t);
            t = fmaf(A0[m].z, w2,  t);
            t = fmaf(A0[m].w, w3v, t);
            t = fmaf(A1[m].x, w4,  t);
            t = fmaf(A1[m].y, w5,  t);
            t = fmaf(A1[m].z, w6,  t);
            t = fmaf(A1[m].w, w7,  t);
            t = fmaf(A2[m].x, w8,  t);
            t = fmaf(A2[m].y, w9,  t);
            t = fmaf(A2[m].z, w10, t);
            t = fmaf(A2[m].w, w11, t);
            t = fmaxf(t, 0.f);
            acc[m] = fmaf(xs[grp * 8 + m][i], t, acc[m]);
        }
    }

    if (c < CC) {
#pragma unroll
        for (int m = 0; m < 8; ++m) {
            int dst = eidx[EE + e0 + m];
            atomicAdd(&aggN[(size_t)dst * CC + c], acc[m]);
        }
    }
}

// h[n][c] = relu(x @ W_root + aggN + bias), natural [N][C] layout.
// lane mapping: 4 nodes x 16 channels per wave, 7 chunks, i-outer.
__global__ __launch_bounds__(256) void root_kernel(
    const float* __restrict__ x, const float* __restrict__ wr2,
    const float* __restrict__ aggN, float* __restrict__ h)
{
    const int lane = threadIdx.x & 63;
    const int wv = threadIdx.x >> 6;
    const int se = lane >> 4;
    const int c15 = lane & 15;
    const int n = blockIdx.x * 16 + wv * 4 + se;

    const float* xr = x + (size_t)n * FA;
    float acc[NCH];
#pragma unroll
    for (int k = 0; k < NCH; ++k) acc[k] = 0.f;

    for (int i = 0; i < FA; ++i) {
        float xi = xr[i];
        const float* wr = wr2 + i * CP + c15;
#pragma unroll
        for (int k = 0; k < NCH; ++k) acc[k] = fmaf(xi, wr[k * 16], acc[k]);
    }

#pragma unroll
    for (int k = 0; k < NCH; ++k) {
        int cc = k * 16 + c15;
        if (cc < CC) {
            float b = wr2[FA * CP + cc];     // bias row
            float v = acc[k] + b + aggN[(size_t)n * CC + cc];
            h[(size_t)n * CC + cc] = fmaxf(v, 0.f);
        }
    }
}

// per-channel sum / sumsq over h[:, c] via f64 atomics (125 partials/channel)
__global__ __launch_bounds__(128) void stats_kernel(
    const float* __restrict__ h, double* __restrict__ stats)
{
    const int c = threadIdx.x;
    if (c >= CC) return;
    const int n0 = blockIdx.x * 160;         // grid 125 -> 20000 nodes
    double s = 0.0, s2 = 0.0;
    for (int n = n0; n < n0 + 160; ++n) {
        float v = h[(size_t)n * CC + c];
        s += (double)v;
        s2 += (double)v * (double)v;
    }
    atomicAdd(&stats[c], s);
    atomicAdd(&stats[CC + c], s2);
}

// fused pool + BN-fold + relu + dot(W_out):
// out[g] = relu(A_c*sum_n h[n][c] + cnt_g*(beta_c - A_c*mean_c)) . W_out + b_out
__global__ __launch_bounds__(128) void poolout_kernel(
    const float* __restrict__ h, const double* __restrict__ stats,
    const float* __restrict__ gamma, const float* __restrict__ beta,
    const int* __restrict__ start, const float* __restrict__ W_out,
    const float* __restrict__ b_out, float* __restrict__ out)
{
    const int g = blockIdx.x;
    const int c = threadIdx.x;
    const int n0 = start[g], n1 = start[g + 1];
    float v = 0.f;
    if (c < CC) {
        float s = 0.f;
        for (int n = n0; n < n1; ++n) s += h[(size_t)n * CC + c];
        double m = stats[c] / NN;
        double var = stats[CC + c] / NN - m * m;
        float mean = (float)m;
        float rstd = rsqrtf((float)var + BN_EPS);
        float A = gamma[c] * rstd;
        float B = beta[c] - A * mean;
        float pooled = fmaf(A, s, (float)(n1 - n0) * B);
        v = fmaxf(pooled, 0.f) * W_out[c];
    }
    __shared__ float sh[128];
    sh[threadIdx.x] = v;
    __syncthreads();
    for (int o = 64; o > 0; o >>= 1) {
        if (threadIdx.x < o) sh[threadIdx.x] += sh[threadIdx.x + o];
        __syncthreads();
    }
    if (threadIdx.x == 0) out[g] = sh[0] + b_out[0];
}

extern "C" void kernel_launch(void* const* d_in, const int* in_sizes, int n_in,
                              void* d_out, int out_size, void* d_ws, size_t ws_size,
                              hipStream_t stream)
{
    const float* x         = (const float*)d_in[0];
    const float* edge_attr = (const float*)d_in[1];
    const float* W1        = (const float*)d_in[2];
    const float* b1        = (const float*)d_in[3];
    const float* W_root    = (const float*)d_in[4];
    const float* bias      = (const float*)d_in[5];
    const float* gamma     = (const float*)d_in[6];
    const float* beta      = (const float*)d_in[7];
    const float* W_out     = (const float*)d_in[8];
    const float* b_out     = (const float*)d_in[9];
    const int*   eidx      = (const int*)d_in[10];
    const int*   batch     = (const int*)d_in[11];

    float*  ws    = (float*)d_ws;
    float*  w3    = ws + OFF_W3;
    float*  wr2   = ws + OFF_WR2;
    float*  aggN  = ws + OFF_AGG;
    double* stats = (double*)(ws + OFF_STAT);
    float*  h     = ws + OFF_H;
    int*    start = (int*)(ws + OFF_START);
    float*  out   = (float*)d_out;

    // zero aggN (2,000,000 f32) + stats (200 f64) in one contiguous memset
    hipMemsetAsync(aggN, 0, (size_t)(2000000 + 400) * sizeof(float), stream);

    prep_kernel<<<(FA * 13 * CW + 76 * CP + 255) / 256, 256, 0, stream>>>(
        W1, b1, W_root, bias, w3, wr2);
    start_kernel<<<(NN + 255) / 256, 256, 0, stream>>>(batch, start);
    msg_kernel<<<EE / 16, 256, 0, stream>>>(x, edge_attr, w3, eidx, aggN);
    root_kernel<<<NN / 16, 256, 0, stream>>>(x, wr2, aggN, h);
    stats_kernel<<<125, 128, 0, stream>>>(h, stats);
    poolout_kernel<<<GG, 128, 0, stream>>>(h, stats, gamma, beta, start,
                                           W_out, b_out, out);
}